// Round 3
// baseline (11510.760 us; speedup 1.0000x reference)
//
#include <hip/hip_runtime.h>
#include <hip/hip_bf16.h>

typedef __attribute__((ext_vector_type(8))) short bf16x8;
typedef __attribute__((ext_vector_type(4))) float f32x4;
typedef unsigned short u16;

__device__ __forceinline__ u16 f2bf(float f) {
  union { float f; unsigned u; } v; v.f = f;
  unsigned r = v.u + 0x7FFFu + ((v.u >> 16) & 1u);   // RTNE
  return (u16)(r >> 16);
}

// ---------------------------------------------------------------------------
// fold: Wt[(j*4+g)][k] = sum_m P[m][j] * (W[k][m] * cos(rx[m]))   (bf16 out)
// ---------------------------------------------------------------------------
__global__ __launch_bounds__(256) void fold_kernel(
    const float* __restrict__ W, const float* __restrict__ rx,
    const float* __restrict__ P, u16* __restrict__ Wt, int g)
{
  __shared__ __align__(16) float As[16][68];   // As[m][j]
  __shared__ __align__(16) float Bs[16][68];   // Bs[m][k]
  const int bk = blockIdx.x;   // k-tile 0..15
  const int bj = blockIdx.y;   // j-tile 0..7
  const int tid = threadIdx.x;
  const int tx = tid & 15;     // k-dir
  const int ty = tid >> 4;     // j-dir
  const int j0 = bj * 64, k0 = bk * 64;
  float acc[4][4] = {};
  for (int m0 = 0; m0 < 512; m0 += 16) {
#pragma unroll
    for (int l = 0; l < 4; ++l) {
      int lin = tid + 256 * l;                 // 0..1023
      int mm = lin >> 6, jr = lin & 63;
      As[mm][jr] = P[(m0 + mm) * 512 + j0 + jr];
      int kk = lin >> 4, mb = lin & 15;
      Bs[mb][kk] = W[(k0 + kk) * 512 + m0 + mb] * cosf(rx[m0 + mb]);
    }
    __syncthreads();
#pragma unroll
    for (int mm = 0; mm < 16; ++mm) {
      f32x4 a = *(const f32x4*)&As[mm][ty * 4];
      f32x4 b = *(const f32x4*)&Bs[mm][tx * 4];
#pragma unroll
      for (int i = 0; i < 4; ++i)
#pragma unroll
        for (int jj = 0; jj < 4; ++jj)
          acc[i][jj] += a[i] * b[jj];
    }
    __syncthreads();
  }
#pragma unroll
  for (int i = 0; i < 4; ++i) {
    int j = j0 + ty * 4 + i;
    size_t n = (size_t)(j * 4 + g);
    ushort4 w;
    w.x = f2bf(acc[i][0]); w.y = f2bf(acc[i][1]);
    w.z = f2bf(acc[i][2]); w.w = f2bf(acc[i][3]);
    *(ushort4*)(Wt + n * 1024 + k0 + tx * 4) = w;
  }
}

// bpn[j*4+g] = sum_m b[m]*cos(rx[m])*P[m][j]
__global__ __launch_bounds__(256) void fold_bias(
    const float* __restrict__ b, const float* __restrict__ rx,
    const float* __restrict__ P, float* __restrict__ bpn, int g)
{
  int j = blockIdx.x * 256 + threadIdx.x;      // 0..511
  float acc = 0.f;
  for (int m = 0; m < 512; ++m) acc += b[m] * cosf(rx[m]) * P[m * 512 + j];
  bpn[j * 4 + g] = acc;
}

// convert whole input X (T*B*D f32) to bf16 once
__global__ __launch_bounds__(256) void xcvt_kernel(
    const float* __restrict__ x, u16* __restrict__ xb)
{
  size_t i = (size_t)blockIdx.x * 256 + threadIdx.x;  // group of 4 elems
  f32x4 v = *(const f32x4*)(x + i * 4);
  ushort4 w;
  w.x = f2bf(v[0]); w.y = f2bf(v[1]); w.z = f2bf(v[2]); w.w = f2bf(v[3]);
  *(ushort4*)(xb + i * 4) = w;
}

// zero hbuf (both parities) + cbuf + flags, every launch (replay determinism)
__global__ __launch_bounds__(256) void init_kernel(unsigned* hbuf32, float* cbuf,
                                                   unsigned* flags) {
  int i = blockIdx.x * 256 + threadIdx.x;      // 65536
  hbuf32[i] = 0;
  cbuf[i] = 0.f;
  if (i < 256) flags[i] = 0;
}

__global__ __launch_bounds__(256) void tail_kernel(
    const float* __restrict__ hlast, const float* __restrict__ c,
    float* __restrict__ hx, float* __restrict__ cx)
{
  int i = blockIdx.x * 256 + threadIdx.x;      // 65536
  hx[i] = hlast[i];
  cx[i] = c[i];
}

// ---------------------------------------------------------------------------
// fallback single-step kernel (R1-proven): pre = [x|h]@W'+b ; gates ; cell
// ---------------------------------------------------------------------------
__global__ __launch_bounds__(256) void step_kernel(
    const u16* __restrict__ xb_t, const u16* __restrict__ h_in,
    u16* __restrict__ h_out, const u16* __restrict__ Wt,
    const float* __restrict__ bpn, float* __restrict__ cbuf,
    float* __restrict__ out_t)
{
  __shared__ float pre_s[32][33];
  const int bid = blockIdx.x;
  const int mb = bid >> 6, nb = bid & 63;
  const int b0 = mb * 32, n0 = nb * 32;
  const int tid = threadIdx.x;
  const int wv = tid >> 6, lane = tid & 63;
  const int rt = wv >> 1, nt = wv & 1;
  const int l15 = lane & 15, kg = lane >> 4;
  const int brow = b0 + rt * 16 + l15;
  const int ncol = n0 + nt * 16 + l15;
  const u16* wrow = Wt + (size_t)ncol * 1024;
  const u16* xrow = xb_t + (size_t)brow * 512;
  const u16* hrow = h_in + (size_t)brow * 512;
  f32x4 acc = {0.f, 0.f, 0.f, 0.f};
#pragma unroll 8
  for (int kk = 0; kk < 32; ++kk) {
    const int kb = kk * 32 + kg * 8;
    bf16x8 bfrag = *(const bf16x8*)(wrow + kb);
    bf16x8 afrag;
    if (kb < 512) afrag = *(const bf16x8*)(xrow + kb);
    else          afrag = *(const bf16x8*)(hrow + (kb - 512));
    acc = __builtin_amdgcn_mfma_f32_16x16x32_bf16(afrag, bfrag, acc, 0, 0, 0);
  }
  const float bias = bpn[ncol];
#pragma unroll
  for (int q = 0; q < 4; ++q)
    pre_s[rt * 16 + kg * 4 + q][nt * 16 + l15] = acc[q] + bias;
  __syncthreads();
  const int bb = tid >> 3, jo = tid & 7;
  float pf = pre_s[bb][jo * 4 + 0];
  float pi = pre_s[bb][jo * 4 + 1];
  float pu = pre_s[bb][jo * 4 + 2];
  float po = pre_s[bb][jo * 4 + 3];
  float fg = 1.f / (1.f + __expf(-pf));
  float ig = 1.f / (1.f + __expf(-pi));
  float gg = tanhf(pu);
  float og = 1.f / (1.f + __expf(-po));
  size_t idx = (size_t)(b0 + bb) * 512 + (size_t)(nb * 8 + jo);
  float cv = fg * cbuf[idx] + ig * gg;
  cbuf[idx] = cv;
  float hv = og * tanhf(cv);
  out_t[idx] = hv;
  h_out[idx] = f2bf(hv);
}

// ---------------------------------------------------------------------------
// persistent recurrence: 256 wgs (4 mb x 64 nb), 256 threads, one kernel.
// Each wave holds its W tile (32 x bf16x8 = 128 VGPR) for all 256 steps.
// One device barrier per step; x-part of t+1 overlaps the barrier wait.
// Spin guard bounds total deadlock time to ~3 s (fails loudly, never hangs).
// ---------------------------------------------------------------------------
__global__ __launch_bounds__(256, 1) void qlstm_persistent(
    const u16* __restrict__ Xbf,    // [256][128][512] bf16
    u16* __restrict__ hbuf,         // [2][128][512] bf16
    const u16* __restrict__ Wt,     // [2048][1024] bf16, n = j*4+g
    const float* __restrict__ bpn,  // [2048] f32
    float* __restrict__ out,        // [256][128][512] + hx + cx
    unsigned* __restrict__ flags)   // [256]
{
  __shared__ float pre_s[32][33];
  const int bid = blockIdx.x;
  const int mb = bid >> 6;           // 0..3
  const int nb = bid & 63;           // 0..63
  const int b0 = mb * 32;
  const int n0 = nb * 32;
  const int tid = threadIdx.x;
  const int wv = tid >> 6;
  const int lane = tid & 63;
  const int rt = wv >> 1;            // row-tile (16 b's)
  const int nt = wv & 1;             // n-tile (16 cols)
  const int l15 = lane & 15;
  const int kg = lane >> 4;          // k-group 0..3
  const int brow = b0 + rt * 16 + l15;
  const int ncol = n0 + nt * 16 + l15;

  // W tile -> registers (once)
  const u16* wrow = Wt + (size_t)ncol * 1024;
  bf16x8 warr[32];
#pragma unroll
  for (int kk = 0; kk < 32; ++kk)
    warr[kk] = *(const bf16x8*)(wrow + kk * 32 + kg * 8);
  const float bnc = bpn[ncol];

  const u16* xbase = Xbf + (size_t)brow * 512;

  const int bb = tid >> 3, jo = tid & 7;
  const size_t eidx = (size_t)(b0 + bb) * 512 + (size_t)(nb * 8 + jo);
  float cst = 0.f, hlast = 0.f;

  // x-part for t=0
  f32x4 accx = {0.f, 0.f, 0.f, 0.f};
#pragma unroll
  for (int kk = 0; kk < 16; ++kk) {
    bf16x8 xv = *(const bf16x8*)(xbase + kk * 32 + kg * 8);
    accx = __builtin_amdgcn_mfma_f32_16x16x32_bf16(xv, warr[kk], accx, 0, 0, 0);
  }

  for (int t = 0; t < 256; ++t) {
    if (t > 0) {
      const unsigned target = (unsigned)t;
      int guard = 0;
      while (__hip_atomic_load(&flags[tid], __ATOMIC_RELAXED,
                               __HIP_MEMORY_SCOPE_AGENT) < target) {
        __builtin_amdgcn_s_sleep(4);
        if (++guard > 100000) break;      // bounded: fail loudly, never hang
      }
      __syncthreads();
      __threadfence();                    // acquire
    }

    // h-part from hbuf[t&1]
    const u16* hr = hbuf + (size_t)((t & 1) ? 65536 : 0) + (size_t)brow * 512;
    f32x4 acch = {0.f, 0.f, 0.f, 0.f};
#pragma unroll
    for (int kk = 0; kk < 16; ++kk) {
      bf16x8 hv = *(const bf16x8*)(hr + kk * 32 + kg * 8);
      acch = __builtin_amdgcn_mfma_f32_16x16x32_bf16(hv, warr[16 + kk], acch, 0, 0, 0);
    }

    // C/D layout: col = lane&15, row = (lane>>4)*4 + q
#pragma unroll
    for (int q = 0; q < 4; ++q)
      pre_s[rt * 16 + kg * 4 + q][nt * 16 + l15] = accx[q] + acch[q] + bnc;
    __syncthreads();

    // gates + cell update
    float pf = pre_s[bb][jo * 4 + 0];
    float pi = pre_s[bb][jo * 4 + 1];
    float pu = pre_s[bb][jo * 4 + 2];
    float po = pre_s[bb][jo * 4 + 3];
    float fg = 1.f / (1.f + __expf(-pf));
    float ig = 1.f / (1.f + __expf(-pi));
    float gg = tanhf(pu);
    float og = 1.f / (1.f + __expf(-po));
    cst = fg * cst + ig * gg;
    float hv = og * tanhf(cst);
    out[(size_t)t * 65536 + eidx] = hv;
    hbuf[(size_t)(((t + 1) & 1) ? 65536 : 0) + eidx] = f2bf(hv);
    hlast = hv;

    __threadfence();                      // release
    __syncthreads();
    if (tid == 0)
      __hip_atomic_store(&flags[bid], (unsigned)(t + 1), __ATOMIC_RELAXED,
                         __HIP_MEMORY_SCOPE_AGENT);

    // x-part for t+1 overlaps other wgs finishing step t
    if (t < 255) {
      const u16* xr = xbase + (size_t)(t + 1) * 65536;
      f32x4 ax = {0.f, 0.f, 0.f, 0.f};
#pragma unroll
      for (int kk = 0; kk < 16; ++kk) {
        bf16x8 xv = *(const bf16x8*)(xr + kk * 32 + kg * 8);
        ax = __builtin_amdgcn_mfma_f32_16x16x32_bf16(xv, warr[kk], ax, 0, 0, 0);
      }
      accx = ax;
    }
  }

  out[(size_t)256 * 65536 + eidx] = hlast;
  out[(size_t)256 * 65536 + 65536 + eidx] = cst;
}

// ---------------------------------------------------------------------------
extern "C" void kernel_launch(void* const* d_in, const int* in_sizes, int n_in,
                              void* d_out, int out_size, void* d_ws, size_t ws_size,
                              hipStream_t stream) {
  (void)in_sizes; (void)n_in; (void)out_size; (void)ws_size;
  const float* inp = (const float*)d_in[0];
  float* out = (float*)d_out;

  // ws layout:
  //   Xbf   : 33,554,432 B
  //   Wt    :  4,194,304 B
  //   bpn   :      8,192 B
  //   hbuf  :    262,144 B (2 x 128 x 512 bf16)
  //   flags :      1,024 B
  //   cbuf  :    262,144 B (fallback path only)
  char* base = (char*)d_ws;
  u16*      Xbf   = (u16*)base;
  u16*      Wt    = (u16*)(base + 33554432);
  float*    bpn   = (float*)(base + 33554432 + 4194304);
  u16*      hbuf  = (u16*)(base + 33554432 + 4194304 + 8192);
  unsigned* flags = (unsigned*)(base + 33554432 + 4194304 + 8192 + 262144);
  float*    cbuf  = (float*)(base + 33554432 + 4194304 + 8192 + 262144 + 1024);

  for (int g = 0; g < 4; ++g) {
    const float* W  = (const float*)d_in[1 + 4 * g];
    const float* b  = (const float*)d_in[2 + 4 * g];
    const float* rx = (const float*)d_in[3 + 4 * g];
    const float* P  = (const float*)d_in[4 + 4 * g];
    fold_kernel<<<dim3(16, 8), 256, 0, stream>>>(W, rx, P, Wt, g);
    fold_bias<<<dim3(2), 256, 0, stream>>>(b, rx, P, bpn, g);
  }
  xcvt_kernel<<<16384, 256, 0, stream>>>(inp, Xbf);
  init_kernel<<<256, 256, 0, stream>>>((unsigned*)hbuf, cbuf, flags);

  void* args[6];
  const u16* Xbf_c = Xbf;
  const u16* Wt_c = Wt;
  const float* bpn_c = bpn;
  u16* hbuf_p = hbuf;
  float* out_p = out;
  unsigned* flags_p = flags;
  args[0] = (void*)&Xbf_c;
  args[1] = (void*)&hbuf_p;
  args[2] = (void*)&Wt_c;
  args[3] = (void*)&bpn_c;
  args[4] = (void*)&out_p;
  args[5] = (void*)&flags_p;
  hipError_t e = hipLaunchCooperativeKernel((const void*)qlstm_persistent,
                                            dim3(256), dim3(256), args, 0, stream);
  if (e != hipSuccess) {
    // fallback: proven multi-launch path
    for (int t = 0; t < 256; ++t) {
      const u16* xb_t  = Xbf + (size_t)t * 65536;
      const u16* h_in  = hbuf + (size_t)(t & 1) * 65536;
      u16*       h_oup = hbuf + (size_t)((t & 1) ^ 1) * 65536;
      float*     out_t = out + (size_t)t * 65536;
      step_kernel<<<256, 256, 0, stream>>>(xb_t, h_in, h_oup, Wt, bpn, cbuf, out_t);
    }
    tail_kernel<<<256, 256, 0, stream>>>(out + (size_t)255 * 65536, cbuf,
                                         out + (size_t)256 * 65536,
                                         out + (size_t)256 * 65536 + 65536);
  }
}

// Round 4
// 2615.647 us; speedup vs baseline: 4.4007x; 4.4007x over previous
//
#include <hip/hip_runtime.h>
#include <hip/hip_bf16.h>

typedef __attribute__((ext_vector_type(8))) short bf16x8;
typedef __attribute__((ext_vector_type(4))) float f32x4;
typedef unsigned short u16;
typedef unsigned int u32;
typedef unsigned long long u64;

__device__ __forceinline__ u16 f2bf(float f) {
  union { float f; unsigned u; } v; v.f = f;
  unsigned r = v.u + 0x7FFFu + ((v.u >> 16) & 1u);   // RTNE
  return (u16)(r >> 16);
}

// coherent (agent-scope, L2-bypassing) 16B load as two relaxed-atomic u64s
__device__ __forceinline__ bf16x8 ld_h16(const u16* p) {
  union { bf16x8 v; u64 q[2]; } u;
  u64* q = (u64*)(void*)p;
  u.q[0] = __hip_atomic_load(q,     __ATOMIC_RELAXED, __HIP_MEMORY_SCOPE_AGENT);
  u.q[1] = __hip_atomic_load(q + 1, __ATOMIC_RELAXED, __HIP_MEMORY_SCOPE_AGENT);
  return u.v;
}

// ---------------------------------------------------------------------------
// fold: Wt[(j*4+g)][k] = sum_m P[m][j] * (W[k][m] * cos(rx[m]))   (bf16 out)
// ---------------------------------------------------------------------------
__global__ __launch_bounds__(256) void fold_kernel(
    const float* __restrict__ W, const float* __restrict__ rx,
    const float* __restrict__ P, u16* __restrict__ Wt, int g)
{
  __shared__ __align__(16) float As[16][68];   // As[m][j]
  __shared__ __align__(16) float Bs[16][68];   // Bs[m][k]
  const int bk = blockIdx.x;   // k-tile 0..15
  const int bj = blockIdx.y;   // j-tile 0..7
  const int tid = threadIdx.x;
  const int tx = tid & 15;     // k-dir
  const int ty = tid >> 4;     // j-dir
  const int j0 = bj * 64, k0 = bk * 64;
  float acc[4][4] = {};
  for (int m0 = 0; m0 < 512; m0 += 16) {
#pragma unroll
    for (int l = 0; l < 4; ++l) {
      int lin = tid + 256 * l;                 // 0..1023
      int mm = lin >> 6, jr = lin & 63;
      As[mm][jr] = P[(m0 + mm) * 512 + j0 + jr];
      int kk = lin >> 4, mb = lin & 15;
      Bs[mb][kk] = W[(k0 + kk) * 512 + m0 + mb] * cosf(rx[m0 + mb]);
    }
    __syncthreads();
#pragma unroll
    for (int mm = 0; mm < 16; ++mm) {
      f32x4 a = *(const f32x4*)&As[mm][ty * 4];
      f32x4 b = *(const f32x4*)&Bs[mm][tx * 4];
#pragma unroll
      for (int i = 0; i < 4; ++i)
#pragma unroll
        for (int jj = 0; jj < 4; ++jj)
          acc[i][jj] += a[i] * b[jj];
    }
    __syncthreads();
  }
#pragma unroll
  for (int i = 0; i < 4; ++i) {
    int j = j0 + ty * 4 + i;
    size_t n = (size_t)(j * 4 + g);
    ushort4 w;
    w.x = f2bf(acc[i][0]); w.y = f2bf(acc[i][1]);
    w.z = f2bf(acc[i][2]); w.w = f2bf(acc[i][3]);
    *(ushort4*)(Wt + n * 1024 + k0 + tx * 4) = w;
  }
}

// bpn[j*4+g] = sum_m b[m]*cos(rx[m])*P[m][j]
__global__ __launch_bounds__(256) void fold_bias(
    const float* __restrict__ b, const float* __restrict__ rx,
    const float* __restrict__ P, float* __restrict__ bpn, int g)
{
  int j = blockIdx.x * 256 + threadIdx.x;      // 0..511
  float acc = 0.f;
  for (int m = 0; m < 512; ++m) acc += b[m] * cosf(rx[m]) * P[m * 512 + j];
  bpn[j * 4 + g] = acc;
}

// convert whole input X (T*B*D f32) to bf16 once
__global__ __launch_bounds__(256) void xcvt_kernel(
    const float* __restrict__ x, u16* __restrict__ xb)
{
  size_t i = (size_t)blockIdx.x * 256 + threadIdx.x;  // group of 4 elems
  f32x4 v = *(const f32x4*)(x + i * 4);
  ushort4 w;
  w.x = f2bf(v[0]); w.y = f2bf(v[1]); w.z = f2bf(v[2]); w.w = f2bf(v[3]);
  *(ushort4*)(xb + i * 4) = w;
}

// zero hbuf (both parities) + cbuf + flags, every launch (replay determinism)
__global__ __launch_bounds__(256) void init_kernel(unsigned* hbuf32, float* cbuf,
                                                   unsigned* flags) {
  int i = blockIdx.x * 256 + threadIdx.x;      // 65536
  hbuf32[i] = 0;
  cbuf[i] = 0.f;
  if (i < 256) flags[i] = 0;
}

__global__ __launch_bounds__(256) void tail_kernel(
    const float* __restrict__ hlast, const float* __restrict__ c,
    float* __restrict__ hx, float* __restrict__ cx)
{
  int i = blockIdx.x * 256 + threadIdx.x;      // 65536
  hx[i] = hlast[i];
  cx[i] = c[i];
}

// ---------------------------------------------------------------------------
// fallback single-step kernel (R1-proven): pre = [x|h]@W'+b ; gates ; cell
// ---------------------------------------------------------------------------
__global__ __launch_bounds__(256) void step_kernel(
    const u16* __restrict__ xb_t, const u16* __restrict__ h_in,
    u16* __restrict__ h_out, const u16* __restrict__ Wt,
    const float* __restrict__ bpn, float* __restrict__ cbuf,
    float* __restrict__ out_t)
{
  __shared__ float pre_s[32][33];
  const int bid = blockIdx.x;
  const int mb = bid >> 6, nb = bid & 63;
  const int b0 = mb * 32, n0 = nb * 32;
  const int tid = threadIdx.x;
  const int wv = tid >> 6, lane = tid & 63;
  const int rt = wv >> 1, nt = wv & 1;
  const int l15 = lane & 15, kg = lane >> 4;
  const int brow = b0 + rt * 16 + l15;
  const int ncol = n0 + nt * 16 + l15;
  const u16* wrow = Wt + (size_t)ncol * 1024;
  const u16* xrow = xb_t + (size_t)brow * 512;
  const u16* hrow = h_in + (size_t)brow * 512;
  f32x4 acc = {0.f, 0.f, 0.f, 0.f};
#pragma unroll 8
  for (int kk = 0; kk < 32; ++kk) {
    const int kb = kk * 32 + kg * 8;
    bf16x8 bfrag = *(const bf16x8*)(wrow + kb);
    bf16x8 afrag;
    if (kb < 512) afrag = *(const bf16x8*)(xrow + kb);
    else          afrag = *(const bf16x8*)(hrow + (kb - 512));
    acc = __builtin_amdgcn_mfma_f32_16x16x32_bf16(afrag, bfrag, acc, 0, 0, 0);
  }
  const float bias = bpn[ncol];
#pragma unroll
  for (int q = 0; q < 4; ++q)
    pre_s[rt * 16 + kg * 4 + q][nt * 16 + l15] = acc[q] + bias;
  __syncthreads();
  const int bb = tid >> 3, jo = tid & 7;
  float pf = pre_s[bb][jo * 4 + 0];
  float pi = pre_s[bb][jo * 4 + 1];
  float pu = pre_s[bb][jo * 4 + 2];
  float po = pre_s[bb][jo * 4 + 3];
  float fg = 1.f / (1.f + __expf(-pf));
  float ig = 1.f / (1.f + __expf(-pi));
  float gg = tanhf(pu);
  float og = 1.f / (1.f + __expf(-po));
  size_t idx = (size_t)(b0 + bb) * 512 + (size_t)(nb * 8 + jo);
  float cv = fg * cbuf[idx] + ig * gg;
  cbuf[idx] = cv;
  float hv = og * tanhf(cv);
  out_t[idx] = hv;
  h_out[idx] = f2bf(hv);
}

// ---------------------------------------------------------------------------
// persistent recurrence, fence-free: all cross-wg traffic via relaxed
// agent-scope atomics (per-op coherent, no buffer_wbl2/buffer_inv).
// 4 independent barrier groups (one per mb): wg (mb,nb) only needs h rows
// from wgs (mb,*), so wave 0 polls just those 64 flags.
// ---------------------------------------------------------------------------
__global__ __launch_bounds__(256, 1) void qlstm_persistent(
    const u16* __restrict__ Xbf,    // [256][128][512] bf16
    u16* __restrict__ hbuf,         // [2][128][512] bf16
    const u16* __restrict__ Wt,     // [2048][1024] bf16, n = j*4+g
    const float* __restrict__ bpn,  // [2048] f32
    float* __restrict__ out,        // [256][128][512] + hx + cx
    unsigned* __restrict__ flags)   // [256]
{
  __shared__ float pre_s[32][33];
  __shared__ u16 h_s[32][8];
  const int bid = blockIdx.x;
  const int mb = bid >> 6;           // 0..3
  const int nb = bid & 63;           // 0..63
  const int b0 = mb * 32;
  const int n0 = nb * 32;
  const int tid = threadIdx.x;
  const int wv = tid >> 6;
  const int lane = tid & 63;
  const int rt = wv >> 1;            // row-tile (16 b's)
  const int nt = wv & 1;             // n-tile (16 cols)
  const int l15 = lane & 15;
  const int kg = lane >> 4;          // k-group 0..3
  const int brow = b0 + rt * 16 + l15;
  const int ncol = n0 + nt * 16 + l15;

  // W tile -> registers (once; no fences in loop so these stay in VGPRs)
  const u16* wrow = Wt + (size_t)ncol * 1024;
  bf16x8 warr[32];
#pragma unroll
  for (int kk = 0; kk < 32; ++kk)
    warr[kk] = *(const bf16x8*)(wrow + kk * 32 + kg * 8);
  const float bnc = bpn[ncol];

  const u16* xbase = Xbf + (size_t)brow * 512;

  const int bb = tid >> 3, jo = tid & 7;
  const size_t eidx = (size_t)(b0 + bb) * 512 + (size_t)(nb * 8 + jo);
  // u32 h-store ownership (threads 0..127): bb2 = tid>>2, jp = tid&3
  const int bb2 = tid >> 2, jp = tid & 3;
  const size_t hw32 = ((size_t)(b0 + bb2) * 512 + (size_t)(nb * 8)) / 2 + jp;
  float cst = 0.f, hlast = 0.f;

  // x-part for t=0
  f32x4 accx = {0.f, 0.f, 0.f, 0.f};
#pragma unroll
  for (int kk = 0; kk < 16; ++kk) {
    bf16x8 xv = *(const bf16x8*)(xbase + kk * 32 + kg * 8);
    accx = __builtin_amdgcn_mfma_f32_16x16x32_bf16(xv, warr[kk], accx, 0, 0, 0);
  }

  for (int t = 0; t < 256; ++t) {
    if (t > 0) {
      if (tid < 64) {                         // wave 0 polls own group's flags
        const unsigned target = (unsigned)t;
        int guard = 0;
        while (__hip_atomic_load(&flags[mb * 64 + tid], __ATOMIC_RELAXED,
                                 __HIP_MEMORY_SCOPE_AGENT) < target) {
          __builtin_amdgcn_s_sleep(2);
          if (++guard > 30000) break;         // bounded: fail loudly, no hang
        }
      }
      __syncthreads();
      asm volatile("" ::: "memory");          // compiler barrier (no codegen)
    }

    // h-part from hbuf[t&1] via coherent loads (bypass possibly-stale L2)
    const u16* hr = hbuf + (size_t)((t & 1) ? 65536 : 0) + (size_t)brow * 512;
    f32x4 acch = {0.f, 0.f, 0.f, 0.f};
#pragma unroll
    for (int kk = 0; kk < 16; ++kk) {
      bf16x8 hv = ld_h16(hr + kk * 32 + kg * 8);
      acch = __builtin_amdgcn_mfma_f32_16x16x32_bf16(hv, warr[16 + kk], acch, 0, 0, 0);
    }

    // C/D layout: col = lane&15, row = (lane>>4)*4 + q
#pragma unroll
    for (int q = 0; q < 4; ++q)
      pre_s[rt * 16 + kg * 4 + q][nt * 16 + l15] = accx[q] + acch[q] + bnc;
    __syncthreads();

    // gates + cell update
    float pf = pre_s[bb][jo * 4 + 0];
    float pi = pre_s[bb][jo * 4 + 1];
    float pu = pre_s[bb][jo * 4 + 2];
    float po = pre_s[bb][jo * 4 + 3];
    float fg = 1.f / (1.f + __expf(-pf));
    float ig = 1.f / (1.f + __expf(-pi));
    float gg = tanhf(pu);
    float og = 1.f / (1.f + __expf(-po));
    cst = fg * cst + ig * gg;
    float hv = og * tanhf(cst);
    out[(size_t)t * 65536 + eidx] = hv;
    h_s[bb][jo] = f2bf(hv);
    hlast = hv;
    __syncthreads();

    // coherent h store (write-through to coherence point), u32 per thread<128
    u32* hwbase = (u32*)(hbuf + (size_t)(((t + 1) & 1) ? 65536 : 0));
    if (tid < 128) {
      u32 val = ((const u32*)h_s)[tid];
      __hip_atomic_store(hwbase + hw32, val, __ATOMIC_RELAXED,
                         __HIP_MEMORY_SCOPE_AGENT);
    }
    __syncthreads();                          // drains vmcnt(0) before barrier
    if (tid == 0)
      __hip_atomic_store(&flags[bid], (unsigned)(t + 1), __ATOMIC_RELAXED,
                         __HIP_MEMORY_SCOPE_AGENT);

    // x-part for t+1 overlaps other wgs finishing step t
    if (t < 255) {
      const u16* xr = xbase + (size_t)(t + 1) * 65536;
      f32x4 ax = {0.f, 0.f, 0.f, 0.f};
#pragma unroll
      for (int kk = 0; kk < 16; ++kk) {
        bf16x8 xv = *(const bf16x8*)(xr + kk * 32 + kg * 8);
        ax = __builtin_amdgcn_mfma_f32_16x16x32_bf16(xv, warr[kk], ax, 0, 0, 0);
      }
      accx = ax;
    }
  }

  out[(size_t)256 * 65536 + eidx] = hlast;
  out[(size_t)256 * 65536 + 65536 + eidx] = cst;
}

// ---------------------------------------------------------------------------
extern "C" void kernel_launch(void* const* d_in, const int* in_sizes, int n_in,
                              void* d_out, int out_size, void* d_ws, size_t ws_size,
                              hipStream_t stream) {
  (void)in_sizes; (void)n_in; (void)out_size; (void)ws_size;
  const float* inp = (const float*)d_in[0];
  float* out = (float*)d_out;

  // ws layout:
  //   Xbf   : 33,554,432 B
  //   Wt    :  4,194,304 B
  //   bpn   :      8,192 B
  //   hbuf  :    262,144 B (2 x 128 x 512 bf16)
  //   flags :      1,024 B
  //   cbuf  :    262,144 B (fallback path only)
  char* base = (char*)d_ws;
  u16*      Xbf   = (u16*)base;
  u16*      Wt    = (u16*)(base + 33554432);
  float*    bpn   = (float*)(base + 33554432 + 4194304);
  u16*      hbuf  = (u16*)(base + 33554432 + 4194304 + 8192);
  unsigned* flags = (unsigned*)(base + 33554432 + 4194304 + 8192 + 262144);
  float*    cbuf  = (float*)(base + 33554432 + 4194304 + 8192 + 262144 + 1024);

  for (int g = 0; g < 4; ++g) {
    const float* W  = (const float*)d_in[1 + 4 * g];
    const float* b  = (const float*)d_in[2 + 4 * g];
    const float* rx = (const float*)d_in[3 + 4 * g];
    const float* P  = (const float*)d_in[4 + 4 * g];
    fold_kernel<<<dim3(16, 8), 256, 0, stream>>>(W, rx, P, Wt, g);
    fold_bias<<<dim3(2), 256, 0, stream>>>(b, rx, P, bpn, g);
  }
  xcvt_kernel<<<16384, 256, 0, stream>>>(inp, Xbf);
  init_kernel<<<256, 256, 0, stream>>>((unsigned*)hbuf, cbuf, flags);

  void* args[6];
  const u16* Xbf_c = Xbf;
  const u16* Wt_c = Wt;
  const float* bpn_c = bpn;
  u16* hbuf_p = hbuf;
  float* out_p = out;
  unsigned* flags_p = flags;
  args[0] = (void*)&Xbf_c;
  args[1] = (void*)&hbuf_p;
  args[2] = (void*)&Wt_c;
  args[3] = (void*)&bpn_c;
  args[4] = (void*)&out_p;
  args[5] = (void*)&flags_p;
  hipError_t e = hipLaunchCooperativeKernel((const void*)qlstm_persistent,
                                            dim3(256), dim3(256), args, 0, stream);
  if (e != hipSuccess) {
    // fallback: proven multi-launch path
    for (int t = 0; t < 256; ++t) {
      const u16* xb_t  = Xbf + (size_t)t * 65536;
      const u16* h_in  = hbuf + (size_t)(t & 1) * 65536;
      u16*       h_oup = hbuf + (size_t)((t & 1) ^ 1) * 65536;
      float*     out_t = out + (size_t)t * 65536;
      step_kernel<<<256, 256, 0, stream>>>(xb_t, h_in, h_oup, Wt, bpn, cbuf, out_t);
    }
    tail_kernel<<<256, 256, 0, stream>>>(out + (size_t)255 * 65536, cbuf,
                                         out + (size_t)256 * 65536,
                                         out + (size_t)256 * 65536 + 65536);
  }
}

// Round 7
// 2118.294 us; speedup vs baseline: 5.4340x; 1.2348x over previous
//
#include <hip/hip_runtime.h>
#include <hip/hip_bf16.h>

typedef __attribute__((ext_vector_type(8))) short bf16x8;
typedef __attribute__((ext_vector_type(4))) float f32x4;
typedef unsigned short u16;
typedef unsigned int u32;
typedef unsigned long long u64;

__device__ __forceinline__ u16 f2bf(float f) {
  union { float f; unsigned u; } v; v.f = f;
  unsigned r = v.u + 0x7FFFu + ((v.u >> 16) & 1u);   // RTNE
  return (u16)(r >> 16);
}

__device__ __forceinline__ float sigm_fast(float x) {
  return __builtin_amdgcn_rcpf(1.f + __expf(-x));
}
__device__ __forceinline__ float tanh_fast(float x) {
  x = fminf(fmaxf(x, -15.f), 15.f);
  float e = __expf(2.f * x);
  return (e - 1.f) * __builtin_amdgcn_rcpf(e + 1.f);
}

// coherent (LLC) 16B load, untracked by compiler -> caller must waitcnt.
// early-clobber: dest tuple must not alias the 64b address pair.
__device__ __forceinline__ void ld_llc_b128(const u16* p, bf16x8& r) {
  asm volatile("global_load_dwordx4 %0, %1, off sc0 sc1"
               : "=&v"(r) : "v"(p));
}
// coherent (LLC) 4B store, untracked -> caller must waitcnt before barrier
__device__ __forceinline__ void st_llc_b32(u32* p, u32 v) {
  asm volatile("global_store_dword %0, %1, off sc0 sc1"
               :: "v"(p), "v"(v) : "memory");
}

// ---------------------------------------------------------------------------
// fold: Wt[(j*4+g)][k] = sum_m P[m][j] * (W[k][m] * cos(rx[m]))   (bf16 out)
// ---------------------------------------------------------------------------
__global__ __launch_bounds__(256) void fold_kernel(
    const float* __restrict__ W, const float* __restrict__ rx,
    const float* __restrict__ P, u16* __restrict__ Wt, int g)
{
  __shared__ __align__(16) float As[16][68];   // As[m][j]
  __shared__ __align__(16) float Bs[16][68];   // Bs[m][k]
  const int bk = blockIdx.x;   // k-tile 0..15
  const int bj = blockIdx.y;   // j-tile 0..7
  const int tid = threadIdx.x;
  const int tx = tid & 15;     // k-dir
  const int ty = tid >> 4;     // j-dir
  const int j0 = bj * 64, k0 = bk * 64;
  float acc[4][4] = {};
  for (int m0 = 0; m0 < 512; m0 += 16) {
#pragma unroll
    for (int l = 0; l < 4; ++l) {
      int lin = tid + 256 * l;                 // 0..1023
      int mm = lin >> 6, jr = lin & 63;
      As[mm][jr] = P[(m0 + mm) * 512 + j0 + jr];
      int kk = lin >> 4, mb = lin & 15;
      Bs[mb][kk] = W[(k0 + kk) * 512 + m0 + mb] * cosf(rx[m0 + mb]);
    }
    __syncthreads();
#pragma unroll
    for (int mm = 0; mm < 16; ++mm) {
      f32x4 a = *(const f32x4*)&As[mm][ty * 4];
      f32x4 b = *(const f32x4*)&Bs[mm][tx * 4];
#pragma unroll
      for (int i = 0; i < 4; ++i)
#pragma unroll
        for (int jj = 0; jj < 4; ++jj)
          acc[i][jj] += a[i] * b[jj];
    }
    __syncthreads();
  }
#pragma unroll
  for (int i = 0; i < 4; ++i) {
    int j = j0 + ty * 4 + i;
    size_t n = (size_t)(j * 4 + g);
    ushort4 w;
    w.x = f2bf(acc[i][0]); w.y = f2bf(acc[i][1]);
    w.z = f2bf(acc[i][2]); w.w = f2bf(acc[i][3]);
    *(ushort4*)(Wt + n * 1024 + k0 + tx * 4) = w;
  }
}

// bpn[j*4+g] = sum_m b[m]*cos(rx[m])*P[m][j]
__global__ __launch_bounds__(256) void fold_bias(
    const float* __restrict__ b, const float* __restrict__ rx,
    const float* __restrict__ P, float* __restrict__ bpn, int g)
{
  int j = blockIdx.x * 256 + threadIdx.x;      // 0..511
  float acc = 0.f;
  for (int m = 0; m < 512; ++m) acc += b[m] * cosf(rx[m]) * P[m * 512 + j];
  bpn[j * 4 + g] = acc;
}

// convert whole input X (T*B*D f32) to bf16 once
__global__ __launch_bounds__(256) void xcvt_kernel(
    const float* __restrict__ x, u16* __restrict__ xb)
{
  size_t i = (size_t)blockIdx.x * 256 + threadIdx.x;  // group of 4 elems
  f32x4 v = *(const f32x4*)(x + i * 4);
  ushort4 w;
  w.x = f2bf(v[0]); w.y = f2bf(v[1]); w.z = f2bf(v[2]); w.w = f2bf(v[3]);
  *(ushort4*)(xb + i * 4) = w;
}

// zero hbuf (both parities) + cbuf + flags, every launch (replay determinism)
__global__ __launch_bounds__(256) void init_kernel(unsigned* hbuf32, float* cbuf,
                                                   unsigned* flags) {
  int i = blockIdx.x * 256 + threadIdx.x;      // 65536
  hbuf32[i] = 0;
  cbuf[i] = 0.f;
  if (i < 256) flags[i] = 0;
}

__global__ __launch_bounds__(256) void tail_kernel(
    const float* __restrict__ hlast, const float* __restrict__ c,
    float* __restrict__ hx, float* __restrict__ cx)
{
  int i = blockIdx.x * 256 + threadIdx.x;      // 65536
  hx[i] = hlast[i];
  cx[i] = c[i];
}

// ---------------------------------------------------------------------------
// fallback single-step kernel (R1-proven)
// ---------------------------------------------------------------------------
__global__ __launch_bounds__(256) void step_kernel(
    const u16* __restrict__ xb_t, const u16* __restrict__ h_in,
    u16* __restrict__ h_out, const u16* __restrict__ Wt,
    const float* __restrict__ bpn, float* __restrict__ cbuf,
    float* __restrict__ out_t)
{
  __shared__ float pre_s[32][33];
  const int bid = blockIdx.x;
  const int mb = bid >> 6, nb = bid & 63;
  const int b0 = mb * 32, n0 = nb * 32;
  const int tid = threadIdx.x;
  const int wv = tid >> 6, lane = tid & 63;
  const int rt = wv >> 1, nt = wv & 1;
  const int l15 = lane & 15, kg = lane >> 4;
  const int brow = b0 + rt * 16 + l15;
  const int ncol = n0 + nt * 16 + l15;
  const u16* wrow = Wt + (size_t)ncol * 1024;
  const u16* xrow = xb_t + (size_t)brow * 512;
  const u16* hrow = h_in + (size_t)brow * 512;
  f32x4 acc = {0.f, 0.f, 0.f, 0.f};
#pragma unroll 8
  for (int kk = 0; kk < 32; ++kk) {
    const int kb = kk * 32 + kg * 8;
    bf16x8 bfrag = *(const bf16x8*)(wrow + kb);
    bf16x8 afrag;
    if (kb < 512) afrag = *(const bf16x8*)(xrow + kb);
    else          afrag = *(const bf16x8*)(hrow + (kb - 512));
    acc = __builtin_amdgcn_mfma_f32_16x16x32_bf16(afrag, bfrag, acc, 0, 0, 0);
  }
  const float bias = bpn[ncol];
#pragma unroll
  for (int q = 0; q < 4; ++q)
    pre_s[rt * 16 + kg * 4 + q][nt * 16 + l15] = acc[q] + bias;
  __syncthreads();
  const int bb = tid >> 3, jo = tid & 7;
  float pf = pre_s[bb][jo * 4 + 0];
  float pi = pre_s[bb][jo * 4 + 1];
  float pu = pre_s[bb][jo * 4 + 2];
  float po = pre_s[bb][jo * 4 + 3];
  float fg = 1.f / (1.f + __expf(-pf));
  float ig = 1.f / (1.f + __expf(-pi));
  float gg = tanhf(pu);
  float og = 1.f / (1.f + __expf(-po));
  size_t idx = (size_t)(b0 + bb) * 512 + (size_t)(nb * 8 + jo);
  float cv = fg * cbuf[idx] + ig * gg;
  cbuf[idx] = cv;
  float hv = og * tanhf(cv);
  out_t[idx] = hv;
  h_out[idx] = f2bf(hv);
}

// ---------------------------------------------------------------------------
// persistent recurrence, fence-free, BATCHED coherent h-loads:
// issue 16 x global_load_dwordx4 sc0 sc1 back-to-back, one waitcnt, then MFMA.
// h-store: shfl-pack 2 x bf16, even lanes store one dword (coherent), explicit
// vmcnt drain before the flag barrier. out[] store moved off critical path.
// ---------------------------------------------------------------------------
__global__ __launch_bounds__(256, 1) void qlstm_persistent(
    const u16* __restrict__ Xbf,    // [256][128][512] bf16
    u16* __restrict__ hbuf,         // [2][128][512] bf16
    const u16* __restrict__ Wt,     // [2048][1024] bf16, n = j*4+g
    const float* __restrict__ bpn,  // [2048] f32
    float* __restrict__ out,        // [256][128][512] + hx + cx
    unsigned* __restrict__ flags)   // [256]
{
  __shared__ float pre_s[32][33];
  const int bid = blockIdx.x;
  const int mb = bid >> 6;           // 0..3
  const int nb = bid & 63;           // 0..63
  const int b0 = mb * 32;
  const int n0 = nb * 32;
  const int tid = threadIdx.x;
  const int wv = tid >> 6;
  const int lane = tid & 63;
  const int rt = wv >> 1;            // row-tile (16 b's)
  const int nt = wv & 1;             // n-tile (16 cols)
  const int l15 = lane & 15;
  const int kg = lane >> 4;          // k-group 0..3
  const int brow = b0 + rt * 16 + l15;
  const int ncol = n0 + nt * 16 + l15;

  // W tile fragments
  const u16* wrow = Wt + (size_t)ncol * 1024;
  bf16x8 warr[32];
#pragma unroll
  for (int kk = 0; kk < 32; ++kk)
    warr[kk] = *(const bf16x8*)(wrow + kk * 32 + kg * 8);
  const float bnc = bpn[ncol];

  const u16* xbase = Xbf + (size_t)brow * 512;

  const int bb = tid >> 3, jo = tid & 7;
  const size_t eidx = (size_t)(b0 + bb) * 512 + (size_t)(nb * 8 + jo);
  float cst = 0.f, hlast = 0.f;

  // x-part for t=0
  f32x4 accx = {0.f, 0.f, 0.f, 0.f};
#pragma unroll
  for (int kk = 0; kk < 16; ++kk) {
    bf16x8 xv = *(const bf16x8*)(xbase + kk * 32 + kg * 8);
    accx = __builtin_amdgcn_mfma_f32_16x16x32_bf16(xv, warr[kk], accx, 0, 0, 0);
  }

  for (int t = 0; t < 256; ++t) {
    if (t > 0) {
      if (tid < 64) {                         // wave 0 polls own group's flags
        const unsigned target = (unsigned)t;
        int guard = 0;
        while (__hip_atomic_load(&flags[mb * 64 + tid], __ATOMIC_RELAXED,
                                 __HIP_MEMORY_SCOPE_AGENT) < target) {
          __builtin_amdgcn_s_sleep(2);
          if (++guard > 30000) break;         // bounded: fail loudly, no hang
        }
      }
      __syncthreads();
      asm volatile("" ::: "memory");
    }

    // ---- batched coherent h loads (one LLC round trip for all 16) ----
    const u16* hr = hbuf + (size_t)((t & 1) ? 65536 : 0) + (size_t)brow * 512;
    bf16x8 hfrag[16];
#pragma unroll
    for (int kk = 0; kk < 16; ++kk)
      ld_llc_b128(hr + kk * 32 + kg * 8, hfrag[kk]);
    asm volatile("s_waitcnt vmcnt(0)" ::: "memory");
    __builtin_amdgcn_sched_barrier(0);        // keep MFMAs below the waitcnt

    f32x4 acch = {0.f, 0.f, 0.f, 0.f};
#pragma unroll
    for (int kk = 0; kk < 16; ++kk)
      acch = __builtin_amdgcn_mfma_f32_16x16x32_bf16(hfrag[kk], warr[16 + kk],
                                                     acch, 0, 0, 0);

    // C/D layout: col = lane&15, row = (lane>>4)*4 + q
#pragma unroll
    for (int q = 0; q < 4; ++q)
      pre_s[rt * 16 + kg * 4 + q][nt * 16 + l15] = accx[q] + acch[q] + bnc;
    __syncthreads();

    // gates + cell update
    float pf = pre_s[bb][jo * 4 + 0];
    float pi = pre_s[bb][jo * 4 + 1];
    float pu = pre_s[bb][jo * 4 + 2];
    float po = pre_s[bb][jo * 4 + 3];
    float fg = sigm_fast(pf);
    float ig = sigm_fast(pi);
    float gg = tanh_fast(pu);
    float og = sigm_fast(po);
    cst = fg * cst + ig * gg;
    float hv = og * tanh_fast(cst);
    hlast = hv;

    // ---- coherent h store: pack 2 bf16 via shfl, even lanes store dword ----
    u16 myh = f2bf(hv);
    u32 partner = (u32)(u16)__shfl_xor((int)(u32)myh, 1);
    u16* hnext = hbuf + (size_t)(((t + 1) & 1) ? 65536 : 0);
    if ((tid & 1) == 0) {
      u32 val = (u32)myh | (partner << 16);
      st_llc_b32((u32*)(hnext + eidx), val);
    }
    asm volatile("s_waitcnt vmcnt(0)" ::: "memory");  // asm stores untracked
    __syncthreads();
    if (tid == 0)
      __hip_atomic_store(&flags[bid], (unsigned)(t + 1), __ATOMIC_RELAXED,
                         __HIP_MEMORY_SCOPE_AGENT);

    // off-critical-path work: out store, then x-part for t+1
    out[(size_t)t * 65536 + eidx] = hv;
    if (t < 255) {
      const u16* xr = xbase + (size_t)(t + 1) * 65536;
      f32x4 ax = {0.f, 0.f, 0.f, 0.f};
#pragma unroll
      for (int kk = 0; kk < 16; ++kk) {
        bf16x8 xv = *(const bf16x8*)(xr + kk * 32 + kg * 8);
        ax = __builtin_amdgcn_mfma_f32_16x16x32_bf16(xv, warr[kk], ax, 0, 0, 0);
      }
      accx = ax;
    }
  }

  out[(size_t)256 * 65536 + eidx] = hlast;
  out[(size_t)256 * 65536 + 65536 + eidx] = cst;
}

// ---------------------------------------------------------------------------
extern "C" void kernel_launch(void* const* d_in, const int* in_sizes, int n_in,
                              void* d_out, int out_size, void* d_ws, size_t ws_size,
                              hipStream_t stream) {
  (void)in_sizes; (void)n_in; (void)out_size; (void)ws_size;
  const float* inp = (const float*)d_in[0];
  float* out = (float*)d_out;

  char* base = (char*)d_ws;
  u16*      Xbf   = (u16*)base;
  u16*      Wt    = (u16*)(base + 33554432);
  float*    bpn   = (float*)(base + 33554432 + 4194304);
  u16*      hbuf  = (u16*)(base + 33554432 + 4194304 + 8192);
  unsigned* flags = (unsigned*)(base + 33554432 + 4194304 + 8192 + 262144);
  float*    cbuf  = (float*)(base + 33554432 + 4194304 + 8192 + 262144 + 1024);

  for (int g = 0; g < 4; ++g) {
    const float* W  = (const float*)d_in[1 + 4 * g];
    const float* b  = (const float*)d_in[2 + 4 * g];
    const float* rx = (const float*)d_in[3 + 4 * g];
    const float* P  = (const float*)d_in[4 + 4 * g];
    fold_kernel<<<dim3(16, 8), 256, 0, stream>>>(W, rx, P, Wt, g);
    fold_bias<<<dim3(2), 256, 0, stream>>>(b, rx, P, bpn, g);
  }
  xcvt_kernel<<<16384, 256, 0, stream>>>(inp, Xbf);
  init_kernel<<<256, 256, 0, stream>>>((unsigned*)hbuf, cbuf, flags);

  void* args[6];
  const u16* Xbf_c = Xbf;
  const u16* Wt_c = Wt;
  const float* bpn_c = bpn;
  u16* hbuf_p = hbuf;
  float* out_p = out;
  unsigned* flags_p = flags;
  args[0] = (void*)&Xbf_c;
  args[1] = (void*)&hbuf_p;
  args[2] = (void*)&Wt_c;
  args[3] = (void*)&bpn_c;
  args[4] = (void*)&out_p;
  args[5] = (void*)&flags_p;
  hipError_t e = hipLaunchCooperativeKernel((const void*)qlstm_persistent,
                                            dim3(256), dim3(256), args, 0, stream);
  if (e != hipSuccess) {
    for (int t = 0; t < 256; ++t) {
      const u16* xb_t  = Xbf + (size_t)t * 65536;
      const u16* h_in  = hbuf + (size_t)(t & 1) * 65536;
      u16*       h_oup = hbuf + (size_t)((t & 1) ^ 1) * 65536;
      float*     out_t = out + (size_t)t * 65536;
      step_kernel<<<256, 256, 0, stream>>>(xb_t, h_in, h_oup, Wt, bpn, cbuf, out_t);
    }
    tail_kernel<<<256, 256, 0, stream>>>(out + (size_t)255 * 65536, cbuf,
                                         out + (size_t)256 * 65536,
                                         out + (size_t)256 * 65536 + 65536);
  }
}